// Round 1
// baseline (650.993 us; speedup 1.0000x reference)
//
#include <hip/hip_runtime.h>
#include <cstdint>
#include <cstddef>

#define NN 100000
#define D 128

// ---------------- degree ----------------
__global__ void k_deg(const int* __restrict__ dst, int ne, int* __restrict__ deg) {
    int e = blockIdx.x * blockDim.x + threadIdx.x;
    if (e < ne) atomicAdd(&deg[dst[e]], 1);
}

__global__ void k_invdeg(const int* __restrict__ deg, float* __restrict__ invd, int n) {
    int i = blockIdx.x * blockDim.x + threadIdx.x;
    if (i < n) invd[i] = 1.0f / fmaxf((float)deg[i], 1.0f);
}

// ---------------- exclusive scan deg -> rowptr (3 kernels) ----------------
__global__ void k_chunk_reduce(const int* __restrict__ deg, int n, int* __restrict__ bsum) {
    __shared__ int s[256];
    int i = blockIdx.x * 256 + threadIdx.x;
    s[threadIdx.x] = (i < n) ? deg[i] : 0;
    __syncthreads();
    for (int off = 128; off > 0; off >>= 1) {
        if (threadIdx.x < off) s[threadIdx.x] += s[threadIdx.x + off];
        __syncthreads();
    }
    if (threadIdx.x == 0) bsum[blockIdx.x] = s[0];
}

__global__ void k_scan_partials(int* __restrict__ bsum, int nb, int* __restrict__ rowptr, int n) {
    if (blockIdx.x == 0 && threadIdx.x == 0) {
        int run = 0;
        for (int b = 0; b < nb; ++b) { int t = bsum[b]; bsum[b] = run; run += t; }
        rowptr[n] = run;
    }
}

__global__ void k_chunk_scan(const int* __restrict__ deg, int n, const int* __restrict__ bsum,
                             int* __restrict__ rowptr) {
    __shared__ int s[256];
    int tid = threadIdx.x;
    int i = blockIdx.x * 256 + tid;
    int v = (i < n) ? deg[i] : 0;
    s[tid] = v;
    __syncthreads();
    for (int off = 1; off < 256; off <<= 1) {
        int t = (tid >= off) ? s[tid - off] : 0;
        __syncthreads();
        s[tid] += t;
        __syncthreads();
    }
    if (i < n) rowptr[i] = bsum[blockIdx.x] + s[tid] - v;  // exclusive
}

// ---------------- CSR fill ----------------
__global__ void k_fill(const int* __restrict__ src, const int* __restrict__ dst, int ne,
                       const int* __restrict__ rowptr, int* __restrict__ cursor,
                       int* __restrict__ col) {
    int e = blockIdx.x * blockDim.x + threadIdx.x;
    if (e < ne) {
        int d = dst[e];
        int p = rowptr[d] + atomicAdd(&cursor[d], 1);
        col[p] = src[e];
    }
}

// ---------------- mean aggregation: one wave per node ----------------
__global__ __launch_bounds__(256) void k_aggregate(const float* __restrict__ h,
                                                   const int* __restrict__ rowptr,
                                                   const int* __restrict__ col,
                                                   const float* __restrict__ invd,
                                                   float* __restrict__ neigh) {
    int node = (blockIdx.x * blockDim.x + threadIdx.x) >> 6;
    int lane = threadIdx.x & 63;
    if (node >= NN) return;
    int e0 = rowptr[node], e1 = rowptr[node + 1];
    float ax = 0.f, ay = 0.f;
    for (int e = e0; e < e1; ++e) {
        int s = col[e];
        const float2 v = *(const float2*)(h + (size_t)s * D + lane * 2);
        ax += v.x; ay += v.y;
    }
    float inv = invd[node];
    float2 o; o.x = ax * inv; o.y = ay * inv;
    *(float2*)(neigh + (size_t)node * D + lane * 2) = o;
}

// ---------------- fused layer GEMM: out = A0@W0 + A1@W1 + b, optional ReLU ----------------
// Block: 256 threads computes 64 rows x 128 cols. Per thread: 4 rows x 8 cols.
__global__ __launch_bounds__(256) void k_layer(const float* __restrict__ A0,
                                               const float* __restrict__ A1,
                                               const float* __restrict__ W0,
                                               const float* __restrict__ W1,
                                               const float* __restrict__ bias,
                                               float* __restrict__ out, int M, int relu) {
    __shared__ float As[64][33];    // +1 pad: conflict-free column reads
    __shared__ float Bs[32][132];   // +4 pad keeps float4 alignment, spreads banks
    int tid = threadIdx.x;
    int tx = tid & 15;   // col group: cols tx*8 .. tx*8+7
    int ty = tid >> 4;   // row group: rows ty*4 .. ty*4+3
    int m0 = blockIdx.x * 64;

    float acc[4][8];
#pragma unroll
    for (int r = 0; r < 4; ++r)
#pragma unroll
        for (int c = 0; c < 8; ++c) acc[r][c] = 0.f;

    for (int mat = 0; mat < 2; ++mat) {
        const float* A = mat ? A1 : A0;
        const float* W = mat ? W1 : W0;
        for (int k0 = 0; k0 < D; k0 += 32) {
            // stage A tile: 64 rows x 32 k, 2 float4 per thread
#pragma unroll
            for (int j = 0; j < 2; ++j) {
                int s = tid + 256 * j;
                int r = s >> 3, c4 = (s & 7) << 2;
                int m = m0 + r;
                float4 v = make_float4(0.f, 0.f, 0.f, 0.f);
                if (m < M) v = *(const float4*)(A + (size_t)m * D + k0 + c4);
                As[r][c4 + 0] = v.x; As[r][c4 + 1] = v.y;
                As[r][c4 + 2] = v.z; As[r][c4 + 3] = v.w;
            }
            // stage B tile: 32 k x 128 cols, 4 float4 per thread
#pragma unroll
            for (int j = 0; j < 4; ++j) {
                int s = tid + 256 * j;
                int r = s >> 5, c4 = (s & 31) << 2;
                float4 v = *(const float4*)(W + (size_t)(k0 + r) * D + c4);
                Bs[r][c4 + 0] = v.x; Bs[r][c4 + 1] = v.y;
                Bs[r][c4 + 2] = v.z; Bs[r][c4 + 3] = v.w;
            }
            __syncthreads();
#pragma unroll
            for (int kk = 0; kk < 32; ++kk) {
                float a[4];
#pragma unroll
                for (int r = 0; r < 4; ++r) a[r] = As[ty * 4 + r][kk];
                float4 b01 = *(const float4*)&Bs[kk][tx * 8];
                float4 b23 = *(const float4*)&Bs[kk][tx * 8 + 4];
                float bb[8] = {b01.x, b01.y, b01.z, b01.w, b23.x, b23.y, b23.z, b23.w};
#pragma unroll
                for (int r = 0; r < 4; ++r)
#pragma unroll
                    for (int c = 0; c < 8; ++c)
                        acc[r][c] = fmaf(a[r], bb[c], acc[r][c]);
            }
            __syncthreads();
        }
    }

    // epilogue: bias (+ReLU), vectorized store
    float4 bv0 = *(const float4*)(bias + tx * 8);
    float4 bv1 = *(const float4*)(bias + tx * 8 + 4);
    float bb[8] = {bv0.x, bv0.y, bv0.z, bv0.w, bv1.x, bv1.y, bv1.z, bv1.w};
#pragma unroll
    for (int r = 0; r < 4; ++r) {
        int m = m0 + ty * 4 + r;
        if (m >= M) continue;
        float o[8];
#pragma unroll
        for (int c = 0; c < 8; ++c) {
            float v = acc[r][c] + bb[c];
            if (relu) v = fmaxf(v, 0.f);
            o[c] = v;
        }
        float4* p = (float4*)(out + (size_t)m * D + tx * 8);
        p[0] = make_float4(o[0], o[1], o[2], o[3]);
        p[1] = make_float4(o[4], o[5], o[6], o[7]);
    }
}

extern "C" void kernel_launch(void* const* d_in, const int* in_sizes, int n_in,
                              void* d_out, int out_size, void* d_ws, size_t ws_size,
                              hipStream_t stream) {
    const float* h   = (const float*)d_in[0];
    const int*   src = (const int*)d_in[1];
    const int*   dst = (const int*)d_in[2];
    const float* Ws  = (const float*)d_in[3];
    const float* Wn  = (const float*)d_in[4];
    const float* b   = (const float*)d_in[5];
    float* out = (float*)d_out;
    int ne = in_sizes[1];

    // workspace carve-up (all offsets 16B-aligned)
    char* ws = (char*)d_ws;
    float* neigh  = (float*)ws;               ws += (size_t)NN * D * sizeof(float);  // 51.2 MB
    int*   deg    = (int*)ws;                 ws += (size_t)NN * sizeof(int);
    int*   cursor = (int*)ws;                 ws += (size_t)NN * sizeof(int);
    int*   rowptr = (int*)ws;                 ws += ((size_t)(NN + 1) * sizeof(int) + 15) / 16 * 16;
    int*   col    = (int*)ws;                 ws += (size_t)ne * sizeof(int);
    int*   bsum   = (int*)ws;                 ws += 512 * sizeof(int);
    float* invd   = (float*)ws;

    hipMemsetAsync(deg, 0, (size_t)NN * sizeof(int), stream);
    hipMemsetAsync(cursor, 0, (size_t)NN * sizeof(int), stream);

    int nchunk = (NN + 255) / 256;  // 391
    k_deg<<<(ne + 255) / 256, 256, 0, stream>>>(dst, ne, deg);
    k_invdeg<<<(NN + 255) / 256, 256, 0, stream>>>(deg, invd, NN);
    k_chunk_reduce<<<nchunk, 256, 0, stream>>>(deg, NN, bsum);
    k_scan_partials<<<1, 64, 0, stream>>>(bsum, nchunk, rowptr, NN);
    k_chunk_scan<<<nchunk, 256, 0, stream>>>(deg, NN, bsum, rowptr);
    k_fill<<<(ne + 255) / 256, 256, 0, stream>>>(src, dst, ne, rowptr, cursor, col);

    const float* cur = h;
    for (int layer = 0; layer < 3; ++layer) {
        k_aggregate<<<(NN + 3) / 4, 256, 0, stream>>>(cur, rowptr, col, invd, neigh);
        k_layer<<<(NN + 63) / 64, 256, 0, stream>>>(cur, neigh,
            Ws + (size_t)layer * D * D, Wn + (size_t)layer * D * D, b + (size_t)layer * D,
            out, NN, (layer < 2) ? 1 : 0);
        cur = out;  // in-place for layers 1,2: each block reads only its own rows
    }
}

// Round 2
// 539.474 us; speedup vs baseline: 1.2067x; 1.2067x over previous
//
#include <hip/hip_runtime.h>
#include <cstdint>
#include <cstddef>

#define NN 100000
#define D 128
#define K2 256  // concat width: [h | neigh]

typedef __attribute__((ext_vector_type(8))) short bf16x8;
typedef __attribute__((ext_vector_type(4))) float f32x4;

__device__ inline float bfhi2f(unsigned int u) {  // high 16 bits as bf16
    union { unsigned int i; float f; } v; v.i = u & 0xffff0000u; return v.f;
}
__device__ inline float bflo2f(unsigned int u) {  // low 16 bits as bf16
    union { unsigned int i; float f; } v; v.i = u << 16; return v.f;
}
__device__ inline unsigned short f2bf(float f) {  // RNE
    union { float f; unsigned int i; } v; v.f = f;
    unsigned int r = v.i + 0x7FFFu + ((v.i >> 16) & 1u);
    return (unsigned short)(r >> 16);
}

// ---------------- degree ----------------
__global__ void k_deg(const int* __restrict__ dst, int ne, int* __restrict__ deg) {
    int e = blockIdx.x * blockDim.x + threadIdx.x;
    if (e < ne) atomicAdd(&deg[dst[e]], 1);
}

__global__ void k_invdeg(const int* __restrict__ deg, float* __restrict__ invd, int n) {
    int i = blockIdx.x * blockDim.x + threadIdx.x;
    if (i < n) invd[i] = 1.0f / fmaxf((float)deg[i], 1.0f);
}

// ---------------- exclusive scan deg -> rowptr ----------------
__global__ void k_chunk_reduce(const int* __restrict__ deg, int n, int* __restrict__ bsum) {
    __shared__ int s[256];
    int i = blockIdx.x * 256 + threadIdx.x;
    s[threadIdx.x] = (i < n) ? deg[i] : 0;
    __syncthreads();
    for (int off = 128; off > 0; off >>= 1) {
        if (threadIdx.x < off) s[threadIdx.x] += s[threadIdx.x + off];
        __syncthreads();
    }
    if (threadIdx.x == 0) bsum[blockIdx.x] = s[0];
}

__global__ void k_scan_partials(int* __restrict__ bsum, int nb, int* __restrict__ rowptr, int n) {
    if (blockIdx.x == 0 && threadIdx.x == 0) {
        int run = 0;
        for (int b = 0; b < nb; ++b) { int t = bsum[b]; bsum[b] = run; run += t; }
        rowptr[n] = run;
    }
}

__global__ void k_chunk_scan(const int* __restrict__ deg, int n, const int* __restrict__ bsum,
                             int* __restrict__ rowptr) {
    __shared__ int s[256];
    int tid = threadIdx.x;
    int i = blockIdx.x * 256 + tid;
    int v = (i < n) ? deg[i] : 0;
    s[tid] = v;
    __syncthreads();
    for (int off = 1; off < 256; off <<= 1) {
        int t = (tid >= off) ? s[tid - off] : 0;
        __syncthreads();
        s[tid] += t;
        __syncthreads();
    }
    if (i < n) rowptr[i] = bsum[blockIdx.x] + s[tid] - v;  // exclusive
}

// ---------------- CSR fill ----------------
__global__ void k_fill(const int* __restrict__ src, const int* __restrict__ dst, int ne,
                       const int* __restrict__ rowptr, int* __restrict__ cursor,
                       int* __restrict__ col) {
    int e = blockIdx.x * blockDim.x + threadIdx.x;
    if (e < ne) {
        int d = dst[e];
        int p = rowptr[d] + atomicAdd(&cursor[d], 1);
        col[p] = src[e];
    }
}

// ---------------- h (fp32) -> A_cat[:,0:128] (bf16) ----------------
__global__ void k_h2bf(const float* __restrict__ h, unsigned short* __restrict__ A) {
    int t = blockIdx.x * 256 + threadIdx.x;
    if (t >= NN * 32) return;
    int row = t >> 5, c4 = (t & 31) << 2;
    float4 v = *(const float4*)(h + (size_t)row * D + c4);
    ushort4 o;
    o.x = f2bf(v.x); o.y = f2bf(v.y); o.z = f2bf(v.z); o.w = f2bf(v.w);
    *(ushort4*)(A + (size_t)row * K2 + c4) = o;
}

// ---------------- weights -> Bt_bf[layer][n][k] (k<128: Ws, else Wn), bf16 ----------------
__global__ void k_wprep(const float* __restrict__ Ws, const float* __restrict__ Wn,
                        unsigned short* __restrict__ Bt) {
    int t = blockIdx.x * 256 + threadIdx.x;
    if (t >= 3 * 128 * 256) return;
    int l = t / (128 * 256), rem = t % (128 * 256);
    int n = rem >> 8, k = rem & 255;
    float v = (k < 128) ? Ws[(size_t)l * D * D + (size_t)k * D + n]
                        : Wn[(size_t)l * D * D + (size_t)(k - 128) * D + n];
    Bt[(size_t)l * 128 * K2 + (size_t)n * K2 + k] = f2bf(v);
}

// ---------------- mean aggregation: one wave per node, bf16 in/out ----------------
__global__ __launch_bounds__(256) void k_agg(unsigned short* __restrict__ A,
                                             const int* __restrict__ rowptr,
                                             const int* __restrict__ col,
                                             const float* __restrict__ invd) {
    int node = (blockIdx.x * 256 + threadIdx.x) >> 6;
    int lane = threadIdx.x & 63;
    if (node >= NN) return;
    int e0 = rowptr[node], e1 = rowptr[node + 1];
    float ax = 0.f, ay = 0.f;
    for (int e = e0; e < e1; ++e) {
        int s = col[e];
        unsigned int u = *(const unsigned int*)(A + (size_t)s * K2 + lane * 2);
        ax += bflo2f(u);
        ay += bfhi2f(u);
    }
    float inv = invd[node];
    unsigned int o = ((unsigned int)f2bf(ay * inv) << 16) | f2bf(ax * inv);
    *(unsigned int*)(A + (size_t)node * K2 + 128 + lane * 2) = o;
}

// ---------------- MFMA GEMM: [M x 256] bf16 @ Bt^T -> [M x 128] ----------------
// Block = 4 waves, 32 rows/wave = 128 rows/block. No LDS: fragments direct from global.
// a_frag: A[row = base + lane%16][k = ks*32 + (lane/16)*8 + j]
// b_frag: Bt[n = nf*16 + lane%16][same k]   (Bt is [128 n][256 k])
// D frag: row = (lane/16)*4 + i, col = lane%16  (within 16x16)
__global__ __launch_bounds__(256) void k_gemm(const unsigned short* __restrict__ A,
                                              const unsigned short* __restrict__ Bt,
                                              const float* __restrict__ bias,
                                              unsigned short* __restrict__ Anext,
                                              float* __restrict__ outf,
                                              int relu, int M) {
    int wid = threadIdx.x >> 6;
    int lane = threadIdx.x & 63;
    int r16 = lane & 15;
    int g = lane >> 4;
    int wrow0 = blockIdx.x * 128 + wid * 32;

    f32x4 acc[2][8];
#pragma unroll
    for (int mf = 0; mf < 2; ++mf)
#pragma unroll
        for (int nf = 0; nf < 8; ++nf) acc[mf][nf] = (f32x4){0.f, 0.f, 0.f, 0.f};

    const unsigned short* arow0 = A + (size_t)(wrow0 + r16) * K2;
    const unsigned short* arow1 = arow0 + (size_t)16 * K2;
    const unsigned short* brow = Bt + (size_t)r16 * K2;

#pragma unroll
    for (int ks = 0; ks < 8; ++ks) {
        int k0 = ks * 32 + g * 8;
        bf16x8 a0 = *(const bf16x8*)(arow0 + k0);
        bf16x8 a1 = *(const bf16x8*)(arow1 + k0);
#pragma unroll
        for (int nf = 0; nf < 8; ++nf) {
            bf16x8 b = *(const bf16x8*)(brow + (size_t)nf * 16 * K2 + k0);
            acc[0][nf] = __builtin_amdgcn_mfma_f32_16x16x32_bf16(a0, b, acc[0][nf], 0, 0, 0);
            acc[1][nf] = __builtin_amdgcn_mfma_f32_16x16x32_bf16(a1, b, acc[1][nf], 0, 0, 0);
        }
    }

#pragma unroll
    for (int nf = 0; nf < 8; ++nf) {
        float bv = bias[nf * 16 + r16];
#pragma unroll
        for (int mf = 0; mf < 2; ++mf) {
#pragma unroll
            for (int i = 0; i < 4; ++i) {
                int row = wrow0 + mf * 16 + g * 4 + i;
                if (row >= M) continue;
                float v = acc[mf][nf][i] + bv;
                if (relu) v = fmaxf(v, 0.f);
                if (outf) outf[(size_t)row * D + nf * 16 + r16] = v;
                else Anext[(size_t)row * K2 + nf * 16 + r16] = f2bf(v);
            }
        }
    }
}

extern "C" void kernel_launch(void* const* d_in, const int* in_sizes, int n_in,
                              void* d_out, int out_size, void* d_ws, size_t ws_size,
                              hipStream_t stream) {
    const float* h = (const float*)d_in[0];
    const int* src = (const int*)d_in[1];
    const int* dst = (const int*)d_in[2];
    const float* Ws = (const float*)d_in[3];
    const float* Wn = (const float*)d_in[4];
    const float* b = (const float*)d_in[5];
    float* out = (float*)d_out;
    int ne = in_sizes[1];

    // workspace carve-up (A_cat first, other arrays after it absorb tail-block overreads)
    char* ws = (char*)d_ws;
    unsigned short* A_cat = (unsigned short*)ws; ws += (size_t)NN * K2 * sizeof(unsigned short);  // 51.2 MB
    int* col = (int*)ws;    ws += (size_t)ne * sizeof(int);                                       // 2.56 MB
    unsigned short* Bt = (unsigned short*)ws; ws += (size_t)3 * 128 * K2 * sizeof(unsigned short);// 192 KB
    int* deg = (int*)ws;    ws += (size_t)NN * sizeof(int);
    int* cursor = (int*)ws; ws += (size_t)NN * sizeof(int);
    int* rowptr = (int*)ws; ws += ((size_t)(NN + 1) * sizeof(int) + 15) / 16 * 16;
    int* bsum = (int*)ws;   ws += 512 * sizeof(int);
    float* invd = (float*)ws;

    hipMemsetAsync(deg, 0, (size_t)NN * sizeof(int), stream);
    hipMemsetAsync(cursor, 0, (size_t)NN * sizeof(int), stream);

    int nchunk = (NN + 255) / 256;  // 391
    k_deg<<<(ne + 255) / 256, 256, 0, stream>>>(dst, ne, deg);
    k_invdeg<<<(NN + 255) / 256, 256, 0, stream>>>(deg, invd, NN);
    k_chunk_reduce<<<nchunk, 256, 0, stream>>>(deg, NN, bsum);
    k_scan_partials<<<1, 64, 0, stream>>>(bsum, nchunk, rowptr, NN);
    k_chunk_scan<<<nchunk, 256, 0, stream>>>(deg, NN, bsum, rowptr);
    k_fill<<<(ne + 255) / 256, 256, 0, stream>>>(src, dst, ne, rowptr, cursor, col);
    k_h2bf<<<(NN * 32 + 255) / 256, 256, 0, stream>>>(h, A_cat);
    k_wprep<<<(3 * 128 * 256 + 255) / 256, 256, 0, stream>>>(Ws, Wn, Bt);

    int ngemm = (NN + 127) / 128;  // 782
    for (int layer = 0; layer < 3; ++layer) {
        k_agg<<<(NN + 3) / 4, 256, 0, stream>>>(A_cat, rowptr, col, invd);
        k_gemm<<<ngemm, 256, 0, stream>>>(A_cat, Bt + (size_t)layer * 128 * K2, b + (size_t)layer * D,
                                          A_cat, (layer == 2) ? out : nullptr, (layer < 2) ? 1 : 0, NN);
    }
}

// Round 3
// 365.715 us; speedup vs baseline: 1.7801x; 1.4751x over previous
//
#include <hip/hip_runtime.h>
#include <cstdint>
#include <cstddef>

#define NN 100000
#define D 128
#define K2 256  // concat width: [h | neigh]

typedef __attribute__((ext_vector_type(8))) short bf16x8;
typedef __attribute__((ext_vector_type(4))) float f32x4;

__device__ inline float bfhi2f(unsigned int u) {  // high 16 bits as bf16
    union { unsigned int i; float f; } v; v.i = u & 0xffff0000u; return v.f;
}
__device__ inline float bflo2f(unsigned int u) {  // low 16 bits as bf16
    union { unsigned int i; float f; } v; v.i = u << 16; return v.f;
}
__device__ inline unsigned short f2bf(float f) {  // RNE
    union { float f; unsigned int i; } v; v.f = f;
    unsigned int r = v.i + 0x7FFFu + ((v.i >> 16) & 1u);
    return (unsigned short)(r >> 16);
}

// ---------------- degree ----------------
__global__ void k_deg(const int* __restrict__ dst, int ne, int* __restrict__ deg) {
    int e = blockIdx.x * blockDim.x + threadIdx.x;
    if (e < ne) atomicAdd(&deg[dst[e]], 1);
}

// ---------------- scan: per-chunk reduce ----------------
__global__ void k_chunk_reduce(const int* __restrict__ deg, int n, int* __restrict__ bsum) {
    __shared__ int s[256];
    int i = blockIdx.x * 256 + threadIdx.x;
    s[threadIdx.x] = (i < n) ? deg[i] : 0;
    __syncthreads();
    for (int off = 128; off > 0; off >>= 1) {
        if (threadIdx.x < off) s[threadIdx.x] += s[threadIdx.x + off];
        __syncthreads();
    }
    if (threadIdx.x == 0) bsum[blockIdx.x] = s[0];
}

// ---------------- scan of partials: one block, parallel (nb <= 512) ----------------
__global__ __launch_bounds__(512) void k_scan_partials(int* __restrict__ bsum, int nb,
                                                       int* __restrict__ rowptr, int n) {
    __shared__ int s[512];
    int tid = threadIdx.x;
    int v = (tid < nb) ? bsum[tid] : 0;
    s[tid] = v;
    __syncthreads();
    for (int off = 1; off < 512; off <<= 1) {
        int t = (tid >= off) ? s[tid - off] : 0;
        __syncthreads();
        s[tid] += t;
        __syncthreads();
    }
    if (tid < nb) bsum[tid] = s[tid] - v;     // exclusive
    if (tid == nb - 1) rowptr[n] = s[tid];    // total edge count
}

// ---------------- per-chunk exclusive scan + invdeg ----------------
__global__ void k_chunk_scan(const int* __restrict__ deg, int n, const int* __restrict__ bsum,
                             int* __restrict__ rowptr, float* __restrict__ invd) {
    __shared__ int s[256];
    int tid = threadIdx.x;
    int i = blockIdx.x * 256 + tid;
    int v = (i < n) ? deg[i] : 0;
    s[tid] = v;
    __syncthreads();
    for (int off = 1; off < 256; off <<= 1) {
        int t = (tid >= off) ? s[tid - off] : 0;
        __syncthreads();
        s[tid] += t;
        __syncthreads();
    }
    if (i < n) {
        rowptr[i] = bsum[blockIdx.x] + s[tid] - v;  // exclusive
        invd[i] = 1.0f / fmaxf((float)v, 1.0f);
    }
}

// ---------------- CSR fill ----------------
__global__ void k_fill(const int* __restrict__ src, const int* __restrict__ dst, int ne,
                       const int* __restrict__ rowptr, int* __restrict__ cursor,
                       int* __restrict__ col) {
    int e = blockIdx.x * blockDim.x + threadIdx.x;
    if (e < ne) {
        int d = dst[e];
        int p = rowptr[d] + atomicAdd(&cursor[d], 1);
        col[p] = src[e];
    }
}

// ---------------- prep: h (fp32) -> A_cat[:,0:128] bf16  AND  weights -> Btf frag-order ----------------
// Btf layout: [l][nf][ks][lane][j] so the GEMM's b-frag load is one coalesced 1KB wave read.
__global__ void k_prep(const float* __restrict__ h, const float* __restrict__ Ws,
                       const float* __restrict__ Wn, unsigned short* __restrict__ A,
                       unsigned short* __restrict__ Btf) {
    int t = blockIdx.x * 256 + threadIdx.x;
    if (t < NN * 32) {
        int row = t >> 5, c4 = (t & 31) << 2;
        float4 v = *(const float4*)(h + (size_t)row * D + c4);
        ushort4 o = make_ushort4(f2bf(v.x), f2bf(v.y), f2bf(v.z), f2bf(v.w));
        *(ushort4*)(A + (size_t)row * K2 + c4) = o;
    } else {
        int t2 = t - NN * 32;
        if (t2 < 3 * 128 * K2) {
            int j = t2 & 7; int rest = t2 >> 3;
            int lane = rest & 63; rest >>= 6;
            int ks = rest & 7; rest >>= 3;
            int nf = rest & 7; int l = rest >> 3;
            int nn = nf * 16 + (lane & 15);
            int k = ks * 32 + (lane >> 4) * 8 + j;
            float v = (k < D) ? Ws[(size_t)l * D * D + (size_t)k * D + nn]
                              : Wn[(size_t)l * D * D + (size_t)(k - D) * D + nn];
            Btf[t2] = f2bf(v);
        }
    }
}

// ---------------- mean aggregation: one wave per node, 8-wide MLP pipeline ----------------
__global__ __launch_bounds__(256) void k_agg(unsigned short* __restrict__ A,
                                             const int* __restrict__ rowptr,
                                             const int* __restrict__ col,
                                             const float* __restrict__ invd) {
    int node = (blockIdx.x * 256 + threadIdx.x) >> 6;
    int lane = threadIdx.x & 63;
    if (node >= NN) return;
    int e0 = rowptr[node];
    int n = rowptr[node + 1] - e0;
    float ax = 0.f, ay = 0.f;
    if (n > 0) {
        for (int base = 0; base < n; base += 8) {
            int s[8];
#pragma unroll
            for (int i = 0; i < 8; ++i) {
                int idx = base + i;
                s[i] = col[e0 + (idx < n ? idx : n - 1)];  // clamped: loads stay independent
            }
            unsigned int u[8];
#pragma unroll
            for (int i = 0; i < 8; ++i)
                u[i] = *(const unsigned int*)(A + (size_t)s[i] * K2 + lane * 2);
#pragma unroll
            for (int i = 0; i < 8; ++i) {
                unsigned int um = (base + i < n) ? u[i] : 0u;  // uniform-cond mask, exact
                ax += bflo2f(um);
                ay += bfhi2f(um);
            }
        }
    }
    float inv = invd[node];
    unsigned int o = ((unsigned int)f2bf(ay * inv) << 16) | f2bf(ax * inv);
    *(unsigned int*)(A + (size_t)node * K2 + 128 + lane * 2) = o;
}

// ---------------- MFMA GEMM: [M x 256] bf16 @ W^T -> [M x 128] ----------------
// Block = 4 waves, 32 rows/wave = 128 rows/block. Fragments direct from global.
// a_frag: A[row = base + lane%16][k = ks*32 + (lane/16)*8 + j]
// b_frag: Btf packed in fragment order -> coalesced 1KB wave loads
// D frag: row = (lane/16)*4 + i, col = lane%16  (within 16x16)
__global__ __launch_bounds__(256) void k_gemm(const unsigned short* __restrict__ A,
                                              const unsigned short* __restrict__ Btf,
                                              const float* __restrict__ bias,
                                              unsigned short* __restrict__ Anext,
                                              float* __restrict__ outf,
                                              int relu, int M) {
    int wid = threadIdx.x >> 6;
    int lane = threadIdx.x & 63;
    int r16 = lane & 15;
    int g = lane >> 4;
    int wrow0 = blockIdx.x * 128 + wid * 32;

    f32x4 acc[2][8];
#pragma unroll
    for (int mf = 0; mf < 2; ++mf)
#pragma unroll
        for (int nf = 0; nf < 8; ++nf) acc[mf][nf] = (f32x4){0.f, 0.f, 0.f, 0.f};

    const unsigned short* arow0 = A + (size_t)(wrow0 + r16) * K2;
    const unsigned short* arow1 = arow0 + (size_t)16 * K2;

#pragma unroll
    for (int ks = 0; ks < 8; ++ks) {
        int k0 = ks * 32 + g * 8;
        bf16x8 a0 = *(const bf16x8*)(arow0 + k0);
        bf16x8 a1 = *(const bf16x8*)(arow1 + k0);
#pragma unroll
        for (int nf = 0; nf < 8; ++nf) {
            bf16x8 b = *(const bf16x8*)(Btf + (size_t)(((nf * 8 + ks) << 6) + lane) * 8);
            acc[0][nf] = __builtin_amdgcn_mfma_f32_16x16x32_bf16(a0, b, acc[0][nf], 0, 0, 0);
            acc[1][nf] = __builtin_amdgcn_mfma_f32_16x16x32_bf16(a1, b, acc[1][nf], 0, 0, 0);
        }
    }

#pragma unroll
    for (int nf = 0; nf < 8; ++nf) {
        float bv = bias[nf * 16 + r16];
#pragma unroll
        for (int mf = 0; mf < 2; ++mf) {
#pragma unroll
            for (int i = 0; i < 4; ++i) {
                int row = wrow0 + mf * 16 + g * 4 + i;
                if (row >= M) continue;
                float v = acc[mf][nf][i] + bv;
                if (relu) v = fmaxf(v, 0.f);
                if (outf) outf[(size_t)row * D + nf * 16 + r16] = v;
                else Anext[(size_t)row * K2 + nf * 16 + r16] = f2bf(v);
            }
        }
    }
}

extern "C" void kernel_launch(void* const* d_in, const int* in_sizes, int n_in,
                              void* d_out, int out_size, void* d_ws, size_t ws_size,
                              hipStream_t stream) {
    const float* h = (const float*)d_in[0];
    const int* src = (const int*)d_in[1];
    const int* dst = (const int*)d_in[2];
    const float* Ws = (const float*)d_in[3];
    const float* Wn = (const float*)d_in[4];
    const float* b = (const float*)d_in[5];
    float* out = (float*)d_out;
    int ne = in_sizes[1];

    // workspace carve-up
    char* ws = (char*)d_ws;
    unsigned short* A_cat = (unsigned short*)ws; ws += (size_t)NN * K2 * sizeof(unsigned short);   // 51.2 MB
    int* col = (int*)ws;    ws += (size_t)ne * sizeof(int);                                        // 2.56 MB
    unsigned short* Btf = (unsigned short*)ws; ws += (size_t)3 * 128 * K2 * sizeof(unsigned short);// 192 KB
    int* deg = (int*)ws;    ws += (size_t)NN * sizeof(int);
    int* cursor = (int*)ws; ws += (size_t)NN * sizeof(int);
    int* rowptr = (int*)ws; ws += ((size_t)(NN + 1) * sizeof(int) + 15) / 16 * 16;
    int* bsum = (int*)ws;   ws += 512 * sizeof(int);
    float* invd = (float*)ws;

    hipMemsetAsync(deg, 0, (size_t)NN * sizeof(int), stream);
    hipMemsetAsync(cursor, 0, (size_t)NN * sizeof(int), stream);

    int nchunk = (NN + 255) / 256;  // 391
    k_deg<<<(ne + 255) / 256, 256, 0, stream>>>(dst, ne, deg);
    k_chunk_reduce<<<nchunk, 256, 0, stream>>>(deg, NN, bsum);
    k_scan_partials<<<1, 512, 0, stream>>>(bsum, nchunk, rowptr, NN);
    k_chunk_scan<<<nchunk, 256, 0, stream>>>(deg, NN, bsum, rowptr, invd);
    k_fill<<<(ne + 255) / 256, 256, 0, stream>>>(src, dst, ne, rowptr, cursor, col);
    int nprep = (NN * 32 + 3 * 128 * K2 + 255) / 256;
    k_prep<<<nprep, 256, 0, stream>>>(h, Ws, Wn, A_cat, Btf);

    int ngemm = (NN + 127) / 128;  // 782
    for (int layer = 0; layer < 3; ++layer) {
        k_agg<<<(NN + 3) / 4, 256, 0, stream>>>(A_cat, rowptr, col, invd);
        k_gemm<<<ngemm, 256, 0, stream>>>(A_cat, Btf + (size_t)layer * 128 * K2, b + (size_t)layer * D,
                                          A_cat, (layer == 2) ? out : nullptr, (layer < 2) ? 1 : 0, NN);
    }
}

// Round 4
// 261.565 us; speedup vs baseline: 2.4888x; 1.3982x over previous
//
#include <hip/hip_runtime.h>
#include <cstdint>
#include <cstddef>

#define NN 100000
#define D 128
#define K2 256  // GEMM K: [h | neigh]

typedef __attribute__((ext_vector_type(8))) short bf16x8;
typedef __attribute__((ext_vector_type(4))) float f32x4;

__device__ inline float bfhi2f(unsigned int u) {
    union { unsigned int i; float f; } v; v.i = u & 0xffff0000u; return v.f;
}
__device__ inline float bflo2f(unsigned int u) {
    union { unsigned int i; float f; } v; v.i = u << 16; return v.f;
}
__device__ inline unsigned short f2bf(float f) {  // RNE
    union { float f; unsigned int i; } v; v.f = f;
    unsigned int r = v.i + 0x7FFFu + ((v.i >> 16) & 1u);
    return (unsigned short)(r >> 16);
}

// ---------------- degree ----------------
__global__ void k_deg(const int* __restrict__ dst, int ne, int* __restrict__ deg) {
    int e = blockIdx.x * blockDim.x + threadIdx.x;
    if (e < ne) atomicAdd(&deg[dst[e]], 1);
}

// ---------------- scan: per-chunk reduce ----------------
__global__ void k_chunk_reduce(const int* __restrict__ deg, int n, int* __restrict__ bsum) {
    __shared__ int s[256];
    int i = blockIdx.x * 256 + threadIdx.x;
    s[threadIdx.x] = (i < n) ? deg[i] : 0;
    __syncthreads();
    for (int off = 128; off > 0; off >>= 1) {
        if (threadIdx.x < off) s[threadIdx.x] += s[threadIdx.x + off];
        __syncthreads();
    }
    if (threadIdx.x == 0) bsum[blockIdx.x] = s[0];
}

// ---------------- scan of partials: one block (nb <= 512) ----------------
__global__ __launch_bounds__(512) void k_scan_partials(int* __restrict__ bsum, int nb,
                                                       int* __restrict__ rowptr, int n) {
    __shared__ int s[512];
    int tid = threadIdx.x;
    int v = (tid < nb) ? bsum[tid] : 0;
    s[tid] = v;
    __syncthreads();
    for (int off = 1; off < 512; off <<= 1) {
        int t = (tid >= off) ? s[tid - off] : 0;
        __syncthreads();
        s[tid] += t;
        __syncthreads();
    }
    if (tid < nb) bsum[tid] = s[tid] - v;
    if (tid == nb - 1) rowptr[n] = s[tid];
}

// ---------------- per-chunk exclusive scan + invdeg ----------------
__global__ void k_chunk_scan(const int* __restrict__ deg, int n, const int* __restrict__ bsum,
                             int* __restrict__ rowptr, float* __restrict__ invd) {
    __shared__ int s[256];
    int tid = threadIdx.x;
    int i = blockIdx.x * 256 + tid;
    int v = (i < n) ? deg[i] : 0;
    s[tid] = v;
    __syncthreads();
    for (int off = 1; off < 256; off <<= 1) {
        int t = (tid >= off) ? s[tid - off] : 0;
        __syncthreads();
        s[tid] += t;
        __syncthreads();
    }
    if (i < n) {
        rowptr[i] = bsum[blockIdx.x] + s[tid] - v;
        invd[i] = 1.0f / fmaxf((float)v, 1.0f);
    }
}

// ---------------- CSR fill ----------------
__global__ void k_fill(const int* __restrict__ src, const int* __restrict__ dst, int ne,
                       const int* __restrict__ rowptr, int* __restrict__ cursor,
                       int* __restrict__ col) {
    int e = blockIdx.x * blockDim.x + threadIdx.x;
    if (e < ne) {
        int d = dst[e];
        int p = rowptr[d] + atomicAdd(&cursor[d], 1);
        col[p] = src[e];
    }
}

// ---------------- prep: h -> Ht bf16, weights -> Btf frag-order ----------------
__global__ void k_prep(const float* __restrict__ h, const float* __restrict__ Ws,
                       const float* __restrict__ Wn, unsigned short* __restrict__ Ht,
                       unsigned short* __restrict__ Btf) {
    int t = blockIdx.x * 256 + threadIdx.x;
    if (t < NN * 32) {
        int row = t >> 5, c4 = (t & 31) << 2;
        float4 v = *(const float4*)(h + (size_t)row * D + c4);
        ushort4 o = make_ushort4(f2bf(v.x), f2bf(v.y), f2bf(v.z), f2bf(v.w));
        *(ushort4*)(Ht + (size_t)row * D + c4) = o;
    } else {
        int t2 = t - NN * 32;
        if (t2 < 3 * 128 * K2) {
            int j = t2 & 7; int rest = t2 >> 3;
            int lane = rest & 63; rest >>= 6;
            int ks = rest & 7; rest >>= 3;
            int nf = rest & 7; int l = rest >> 3;
            int nn = nf * 16 + (lane & 15);
            int k = ks * 32 + (lane >> 4) * 8 + j;
            float v = (k < D) ? Ws[(size_t)l * D * D + (size_t)k * D + nn]
                              : Wn[(size_t)l * D * D + (size_t)(k - D) * D + nn];
            Btf[t2] = f2bf(v);
        }
    }
}

// ---------------- mean aggregation: one wave per node, 8-wide load pipeline ----------------
__global__ __launch_bounds__(256) void k_agg(const unsigned short* __restrict__ Ht,
                                             unsigned short* __restrict__ Nt,
                                             const int* __restrict__ rowptr,
                                             const int* __restrict__ col,
                                             const float* __restrict__ invd) {
    int node = (blockIdx.x * 256 + threadIdx.x) >> 6;
    int lane = threadIdx.x & 63;
    if (node >= NN) return;
    int e0 = rowptr[node];
    int n = rowptr[node + 1] - e0;
    float ax = 0.f, ay = 0.f;
    if (n > 0) {
        for (int base = 0; base < n; base += 8) {
            int s[8];
#pragma unroll
            for (int i = 0; i < 8; ++i) {
                int idx = base + i;
                s[i] = col[e0 + (idx < n ? idx : n - 1)];
            }
            unsigned int u[8];
#pragma unroll
            for (int i = 0; i < 8; ++i)
                u[i] = *(const unsigned int*)(Ht + (size_t)s[i] * D + lane * 2);
#pragma unroll
            for (int i = 0; i < 8; ++i) {
                unsigned int um = (base + i < n) ? u[i] : 0u;
                ax += bflo2f(um);
                ay += bfhi2f(um);
            }
        }
    }
    float inv = invd[node];
    unsigned int o = ((unsigned int)f2bf(ay * inv) << 16) | f2bf(ax * inv);
    *(unsigned int*)(Nt + (size_t)node * D + lane * 2) = o;
}

// ---------------- MFMA GEMM: [64 rows x K2] @ W^T -> [64 x 128] per block ----------------
// 4 waves; wave w owns n-fragments {w, w+4} -> B stays in registers (loaded once).
// A-tile staged to LDS via global_load_lds (linear dest) with XOR-swizzled global source;
// ds_read_b128 a-frags apply the same XOR -> conflict-free (2 lanes/bank).
__global__ __launch_bounds__(256, 3) void k_gemm(const unsigned short* __restrict__ Ht,
                                                 const unsigned short* __restrict__ Btf,
                                                 const float* __restrict__ bias,
                                                 unsigned short* __restrict__ HtW,
                                                 float* __restrict__ outf,
                                                 int relu, int M) {
    __shared__ unsigned short Alds[64 * K2];  // 32 KB, rows of 512B: [h(256B) | neigh(256B)]
    int wid = threadIdx.x >> 6;
    int lane = threadIdx.x & 63;
    int r16 = lane & 15;
    int g = lane >> 4;
    int m0 = blockIdx.x * 64;

    // B fragments in registers: wave w -> nf = w and w+4, all 8 k-slices
    bf16x8 bfr[2][8];
#pragma unroll
    for (int q = 0; q < 2; ++q) {
        int nf = wid + q * 4;
#pragma unroll
        for (int ks = 0; ks < 8; ++ks)
            bfr[q][ks] = *(const bf16x8*)(Btf + (size_t)(((nf * 8 + ks) << 6) + lane) * 8);
    }

    // stage A-tile: 32 x 1KB issues, 8 per wave. dest linear, source XOR-swizzled.
    // dest offset o: row = o>>9, half = (o>>8)&1 (h vs neigh), cb = o&255.
    // source element = (row, (cb ^ ((row&7)<<4)) / 2) of Ht (+NN*D if neigh half).
#pragma unroll
    for (int i = 0; i < 8; ++i) {
        int chunk = wid * 8 + i;
        int o = chunk * 1024 + lane * 16;
        int row = o >> 9;
        int half = (o >> 8) & 1;
        int cb = o & 255;
        int scb = cb ^ ((row & 7) << 4);
        const unsigned short* gsrc = Ht + (size_t)(m0 + row) * D + (size_t)half * ((size_t)NN * D) + (scb >> 1);
        __builtin_amdgcn_global_load_lds(
            (const __attribute__((address_space(1))) unsigned int*)gsrc,
            (__attribute__((address_space(3))) unsigned int*)((char*)Alds + chunk * 1024),
            16, 0, 0);
    }
    __syncthreads();

    f32x4 acc[4][2];
#pragma unroll
    for (int mt = 0; mt < 4; ++mt)
#pragma unroll
        for (int q = 0; q < 2; ++q) acc[mt][q] = (f32x4){0.f, 0.f, 0.f, 0.f};

#pragma unroll
    for (int mt = 0; mt < 4; ++mt) {
        int row = mt * 16 + r16;
        bf16x8 a[8];
#pragma unroll
        for (int ks = 0; ks < 8; ++ks) {
            int kb = (ks * 32 + g * 8) * 2;           // byte col in 512B row
            int c = kb ^ ((row & 7) << 4);
            a[ks] = *(const bf16x8*)((const char*)Alds + row * 512 + c);
        }
#pragma unroll
        for (int ks = 0; ks < 8; ++ks) {
            acc[mt][0] = __builtin_amdgcn_mfma_f32_16x16x32_bf16(a[ks], bfr[0][ks], acc[mt][0], 0, 0, 0);
            acc[mt][1] = __builtin_amdgcn_mfma_f32_16x16x32_bf16(a[ks], bfr[1][ks], acc[mt][1], 0, 0, 0);
        }
    }

    // epilogue: D-frag row = g*4+i, col = r16 (within 16x16)
    float bv[2];
    bv[0] = bias[wid * 16 + r16];
    bv[1] = bias[(wid + 4) * 16 + r16];
#pragma unroll
    for (int mt = 0; mt < 4; ++mt) {
#pragma unroll
        for (int q = 0; q < 2; ++q) {
            int colc = (wid + q * 4) * 16 + r16;
#pragma unroll
            for (int i = 0; i < 4; ++i) {
                int row = m0 + mt * 16 + g * 4 + i;
                if (row >= M) continue;
                float v = acc[mt][q][i] + bv[q];
                if (relu) v = fmaxf(v, 0.f);
                if (outf) outf[(size_t)row * D + colc] = v;
                else HtW[(size_t)row * D + colc] = f2bf(v);
            }
        }
    }
}

extern "C" void kernel_launch(void* const* d_in, const int* in_sizes, int n_in,
                              void* d_out, int out_size, void* d_ws, size_t ws_size,
                              hipStream_t stream) {
    const float* h = (const float*)d_in[0];
    const int* src = (const int*)d_in[1];
    const int* dst = (const int*)d_in[2];
    const float* Ws = (const float*)d_in[3];
    const float* Wn = (const float*)d_in[4];
    const float* b = (const float*)d_in[5];
    float* out = (float*)d_out;
    int ne = in_sizes[1];

    // workspace: Ht and Nt adjacent (gemm stages with one base + half*NN*D offset)
    char* ws = (char*)d_ws;
    unsigned short* Ht = (unsigned short*)ws; ws += (size_t)NN * D * sizeof(unsigned short);  // 25.6 MB
    unsigned short* Nt = (unsigned short*)ws; ws += (size_t)NN * D * sizeof(unsigned short);  // 25.6 MB
    int* col = (int*)ws;    ws += (size_t)ne * sizeof(int);                                   // 2.56 MB
    unsigned short* Btf = (unsigned short*)ws; ws += (size_t)3 * 128 * K2 * sizeof(unsigned short);
    int* deg = (int*)ws;    ws += (size_t)NN * sizeof(int);
    int* cursor = (int*)ws; ws += (size_t)NN * sizeof(int);
    int* rowptr = (int*)ws; ws += ((size_t)(NN + 1) * sizeof(int) + 15) / 16 * 16;
    int* bsum = (int*)ws;   ws += 512 * sizeof(int);
    float* invd = (float*)ws;

    hipMemsetAsync(deg, 0, (size_t)NN * sizeof(int), stream);
    hipMemsetAsync(cursor, 0, (size_t)NN * sizeof(int), stream);

    int nchunk = (NN + 255) / 256;  // 391
    k_deg<<<(ne + 255) / 256, 256, 0, stream>>>(dst, ne, deg);
    k_chunk_reduce<<<nchunk, 256, 0, stream>>>(deg, NN, bsum);
    k_scan_partials<<<1, 512, 0, stream>>>(bsum, nchunk, rowptr, NN);
    k_chunk_scan<<<nchunk, 256, 0, stream>>>(deg, NN, bsum, rowptr, invd);
    k_fill<<<(ne + 255) / 256, 256, 0, stream>>>(src, dst, ne, rowptr, cursor, col);
    int nprep = (NN * 32 + 3 * 128 * K2 + 255) / 256;
    k_prep<<<nprep, 256, 0, stream>>>(h, Ws, Wn, Ht, Btf);

    int ngemm = (NN + 63) / 64;  // 1563
    for (int layer = 0; layer < 3; ++layer) {
        k_agg<<<(NN + 3) / 4, 256, 0, stream>>>(Ht, Nt, rowptr, col, invd);
        k_gemm<<<ngemm, 256, 0, stream>>>(Ht, Btf + (size_t)layer * 128 * K2, b + (size_t)layer * D,
                                          Ht, (layer == 2) ? out : nullptr, (layer < 2) ? 1 : 0, NN);
    }
}

// Round 5
// 259.197 us; speedup vs baseline: 2.5116x; 1.0091x over previous
//
#include <hip/hip_runtime.h>
#include <cstdint>
#include <cstddef>

#define NN 100000
#define D 128
#define K2 256  // GEMM K: [h | neigh]

typedef __attribute__((ext_vector_type(8))) short bf16x8;
typedef __attribute__((ext_vector_type(4))) float f32x4;

__device__ inline float bfhi2f(unsigned int u) {
    union { unsigned int i; float f; } v; v.i = u & 0xffff0000u; return v.f;
}
__device__ inline float bflo2f(unsigned int u) {
    union { unsigned int i; float f; } v; v.i = u << 16; return v.f;
}
__device__ inline unsigned short f2bf(float f) {  // RNE
    union { float f; unsigned int i; } v; v.f = f;
    unsigned int r = v.i + 0x7FFFu + ((v.i >> 16) & 1u);
    return (unsigned short)(r >> 16);
}

// ---------------- zero deg (replaces 39us rocclr fill) ----------------
__global__ void k_zero(int4* __restrict__ p, int n4) {
    int t = blockIdx.x * 256 + threadIdx.x;
    if (t < n4) p[t] = make_int4(0, 0, 0, 0);
}

// ---------------- degree ----------------
__global__ void k_deg(const int* __restrict__ dst, int ne, int* __restrict__ deg) {
    int e = blockIdx.x * blockDim.x + threadIdx.x;
    if (e < ne) atomicAdd(&deg[dst[e]], 1);
}

// ---------------- scan: per-chunk reduce ----------------
__global__ void k_chunk_reduce(const int* __restrict__ deg, int n, int* __restrict__ bsum) {
    __shared__ int s[256];
    int i = blockIdx.x * 256 + threadIdx.x;
    s[threadIdx.x] = (i < n) ? deg[i] : 0;
    __syncthreads();
    for (int off = 128; off > 0; off >>= 1) {
        if (threadIdx.x < off) s[threadIdx.x] += s[threadIdx.x + off];
        __syncthreads();
    }
    if (threadIdx.x == 0) bsum[blockIdx.x] = s[0];
}

// ---------------- scan of partials: one block (nb <= 512) ----------------
__global__ __launch_bounds__(512) void k_scan_partials(int* __restrict__ bsum, int nb,
                                                       int* __restrict__ rowptr, int n) {
    __shared__ int s[512];
    int tid = threadIdx.x;
    int v = (tid < nb) ? bsum[tid] : 0;
    s[tid] = v;
    __syncthreads();
    for (int off = 1; off < 512; off <<= 1) {
        int t = (tid >= off) ? s[tid - off] : 0;
        __syncthreads();
        s[tid] += t;
        __syncthreads();
    }
    if (tid < nb) bsum[tid] = s[tid] - v;
    if (tid == nb - 1) rowptr[n] = s[tid];
}

// ---------------- per-chunk exclusive scan + invdeg + cursor init ----------------
__global__ void k_chunk_scan(const int* __restrict__ deg, int n, const int* __restrict__ bsum,
                             int* __restrict__ rowptr, int* __restrict__ cursor,
                             float* __restrict__ invd) {
    __shared__ int s[256];
    int tid = threadIdx.x;
    int i = blockIdx.x * 256 + tid;
    int v = (i < n) ? deg[i] : 0;
    s[tid] = v;
    __syncthreads();
    for (int off = 1; off < 256; off <<= 1) {
        int t = (tid >= off) ? s[tid - off] : 0;
        __syncthreads();
        s[tid] += t;
        __syncthreads();
    }
    if (i < n) {
        int excl = bsum[blockIdx.x] + s[tid] - v;
        rowptr[i] = excl;
        cursor[i] = excl;  // k_fill bumps this directly
        invd[i] = 1.0f / fmaxf((float)v, 1.0f);
    }
}

// ---------------- CSR fill (cursor pre-seeded with rowptr) ----------------
__global__ void k_fill(const int* __restrict__ src, const int* __restrict__ dst, int ne,
                       int* __restrict__ cursor, int* __restrict__ col) {
    int e = blockIdx.x * blockDim.x + threadIdx.x;
    if (e < ne) {
        int p = atomicAdd(&cursor[dst[e]], 1);
        col[p] = src[e];
    }
}

// ---------------- prep: h -> Ht bf16, weights -> Btf frag-order ----------------
__global__ void k_prep(const float* __restrict__ h, const float* __restrict__ Ws,
                       const float* __restrict__ Wn, unsigned short* __restrict__ Ht,
                       unsigned short* __restrict__ Btf) {
    int t = blockIdx.x * 256 + threadIdx.x;
    if (t < NN * 32) {
        int row = t >> 5, c4 = (t & 31) << 2;
        float4 v = *(const float4*)(h + (size_t)row * D + c4);
        ushort4 o = make_ushort4(f2bf(v.x), f2bf(v.y), f2bf(v.z), f2bf(v.w));
        *(ushort4*)(Ht + (size_t)row * D + c4) = o;
    } else {
        int t2 = t - NN * 32;
        if (t2 < 3 * 128 * K2) {
            int j = t2 & 7; int rest = t2 >> 3;
            int lane = rest & 63; rest >>= 6;
            int ks = rest & 7; rest >>= 3;
            int nf = rest & 7; int l = rest >> 3;
            int nn = nf * 16 + (lane & 15);
            int k = ks * 32 + (lane >> 4) * 8 + j;
            float v = (k < D) ? Ws[(size_t)l * D * D + (size_t)k * D + nn]
                              : Wn[(size_t)l * D * D + (size_t)(k - D) * D + nn];
            Btf[t2] = f2bf(v);
        }
    }
}

// ---------------- mean aggregation: one wave per node, 8-wide load pipeline ----------------
__global__ __launch_bounds__(256) void k_agg(const unsigned short* __restrict__ Ht,
                                             unsigned short* __restrict__ Nt,
                                             const int* __restrict__ rowptr,
                                             const int* __restrict__ col,
                                             const float* __restrict__ invd) {
    int node = (blockIdx.x * 256 + threadIdx.x) >> 6;
    int lane = threadIdx.x & 63;
    if (node >= NN) return;
    int e0 = rowptr[node];
    int n = rowptr[node + 1] - e0;
    float ax = 0.f, ay = 0.f;
    if (n > 0) {
        for (int base = 0; base < n; base += 8) {
            int s[8];
#pragma unroll
            for (int i = 0; i < 8; ++i) {
                int idx = base + i;
                s[i] = col[e0 + (idx < n ? idx : n - 1)];
            }
            unsigned int u[8];
#pragma unroll
            for (int i = 0; i < 8; ++i)
                u[i] = *(const unsigned int*)(Ht + (size_t)s[i] * D + lane * 2);
#pragma unroll
            for (int i = 0; i < 8; ++i) {
                unsigned int um = (base + i < n) ? u[i] : 0u;
                ax += bflo2f(um);
                ay += bfhi2f(um);
            }
        }
    }
    float inv = invd[node];
    unsigned int o = ((unsigned int)f2bf(ay * inv) << 16) | f2bf(ax * inv);
    *(unsigned int*)(Nt + (size_t)node * D + lane * 2) = o;
}

// ---------------- MFMA GEMM: [64 rows x K2] @ W^T -> [64 x 128] per block ----------------
// 4 waves; wave w owns n-fragments {w, w+4} -> B stays in registers (loaded once).
// A-tile staged to LDS via global_load_lds (linear dest) with XOR-swizzled global source;
// ds_read_b128 a-frags apply the same XOR -> conflict-free (2 lanes/bank).
__global__ __launch_bounds__(256, 3) void k_gemm(const unsigned short* __restrict__ Ht,
                                                 const unsigned short* __restrict__ Btf,
                                                 const float* __restrict__ bias,
                                                 unsigned short* __restrict__ HtW,
                                                 float* __restrict__ outf,
                                                 int relu, int M) {
    __shared__ unsigned short Alds[64 * K2];  // 32 KB, rows of 512B: [h(256B) | neigh(256B)]
    int wid = threadIdx.x >> 6;
    int lane = threadIdx.x & 63;
    int r16 = lane & 15;
    int g = lane >> 4;
    int m0 = blockIdx.x * 64;

    // B fragments in registers: wave w -> nf = w and w+4, all 8 k-slices
    bf16x8 bfr[2][8];
#pragma unroll
    for (int q = 0; q < 2; ++q) {
        int nf = wid + q * 4;
#pragma unroll
        for (int ks = 0; ks < 8; ++ks)
            bfr[q][ks] = *(const bf16x8*)(Btf + (size_t)(((nf * 8 + ks) << 6) + lane) * 8);
    }

    // stage A-tile: 32 x 1KB issues, 8 per wave. dest linear, source XOR-swizzled.
#pragma unroll
    for (int i = 0; i < 8; ++i) {
        int chunk = wid * 8 + i;
        int o = chunk * 1024 + lane * 16;
        int row = o >> 9;
        int half = (o >> 8) & 1;
        int cb = o & 255;
        int scb = cb ^ ((row & 7) << 4);
        const unsigned short* gsrc = Ht + (size_t)(m0 + row) * D + (size_t)half * ((size_t)NN * D) + (scb >> 1);
        __builtin_amdgcn_global_load_lds(
            (const __attribute__((address_space(1))) unsigned int*)gsrc,
            (__attribute__((address_space(3))) unsigned int*)((char*)Alds + chunk * 1024),
            16, 0, 0);
    }
    __syncthreads();

    f32x4 acc[4][2];
#pragma unroll
    for (int mt = 0; mt < 4; ++mt)
#pragma unroll
        for (int q = 0; q < 2; ++q) acc[mt][q] = (f32x4){0.f, 0.f, 0.f, 0.f};

#pragma unroll
    for (int mt = 0; mt < 4; ++mt) {
        int row = mt * 16 + r16;
        bf16x8 a[8];
#pragma unroll
        for (int ks = 0; ks < 8; ++ks) {
            int kb = (ks * 32 + g * 8) * 2;           // byte col in 512B row
            int c = kb ^ ((row & 7) << 4);
            a[ks] = *(const bf16x8*)((const char*)Alds + row * 512 + c);
        }
#pragma unroll
        for (int ks = 0; ks < 8; ++ks) {
            acc[mt][0] = __builtin_amdgcn_mfma_f32_16x16x32_bf16(a[ks], bfr[0][ks], acc[mt][0], 0, 0, 0);
            acc[mt][1] = __builtin_amdgcn_mfma_f32_16x16x32_bf16(a[ks], bfr[1][ks], acc[mt][1], 0, 0, 0);
        }
    }

    // epilogue: D-frag row = g*4+i, col = r16 (within 16x16)
    float bv[2];
    bv[0] = bias[wid * 16 + r16];
    bv[1] = bias[(wid + 4) * 16 + r16];
#pragma unroll
    for (int mt = 0; mt < 4; ++mt) {
#pragma unroll
        for (int q = 0; q < 2; ++q) {
            int colc = (wid + q * 4) * 16 + r16;
#pragma unroll
            for (int i = 0; i < 4; ++i) {
                int row = m0 + mt * 16 + g * 4 + i;
                if (row >= M) continue;
                float v = acc[mt][q][i] + bv[q];
                if (relu) v = fmaxf(v, 0.f);
                if (outf) outf[(size_t)row * D + colc] = v;
                else HtW[(size_t)row * D + colc] = f2bf(v);
            }
        }
    }
}

extern "C" void kernel_launch(void* const* d_in, const int* in_sizes, int n_in,
                              void* d_out, int out_size, void* d_ws, size_t ws_size,
                              hipStream_t stream) {
    const float* h = (const float*)d_in[0];
    const int* src = (const int*)d_in[1];
    const int* dst = (const int*)d_in[2];
    const float* Ws = (const float*)d_in[3];
    const float* Wn = (const float*)d_in[4];
    const float* b = (const float*)d_in[5];
    float* out = (float*)d_out;
    int ne = in_sizes[1];

    // workspace: Ht and Nt adjacent (gemm stages with one base + half*NN*D offset)
    char* ws = (char*)d_ws;
    unsigned short* Ht = (unsigned short*)ws; ws += (size_t)NN * D * sizeof(unsigned short);  // 25.6 MB
    unsigned short* Nt = (unsigned short*)ws; ws += (size_t)NN * D * sizeof(unsigned short);  // 25.6 MB
    int* col = (int*)ws;    ws += (size_t)ne * sizeof(int);                                   // 2.56 MB
    unsigned short* Btf = (unsigned short*)ws; ws += (size_t)3 * 128 * K2 * sizeof(unsigned short);
    int* deg = (int*)ws;    ws += (size_t)NN * sizeof(int);
    int* cursor = (int*)ws; ws += (size_t)NN * sizeof(int);
    int* rowptr = (int*)ws; ws += ((size_t)(NN + 1) * sizeof(int) + 15) / 16 * 16;
    int* bsum = (int*)ws;   ws += 512 * sizeof(int);
    float* invd = (float*)ws;

    int nchunk = (NN + 255) / 256;  // 391
    k_zero<<<(NN / 4 + 255) / 256, 256, 0, stream>>>((int4*)deg, NN / 4);
    k_deg<<<(ne + 255) / 256, 256, 0, stream>>>(dst, ne, deg);
    k_chunk_reduce<<<nchunk, 256, 0, stream>>>(deg, NN, bsum);
    k_scan_partials<<<1, 512, 0, stream>>>(bsum, nchunk, rowptr, NN);
    k_chunk_scan<<<nchunk, 256, 0, stream>>>(deg, NN, bsum, rowptr, cursor, invd);
    k_fill<<<(ne + 255) / 256, 256, 0, stream>>>(src, dst, ne, cursor, col);
    int nprep = (NN * 32 + 3 * 128 * K2 + 255) / 256;
    k_prep<<<nprep, 256, 0, stream>>>(h, Ws, Wn, Ht, Btf);

    int ngemm = (NN + 63) / 64;  // 1563
    for (int layer = 0; layer < 3; ++layer) {
        k_agg<<<(NN + 3) / 4, 256, 0, stream>>>(Ht, Nt, rowptr, col, invd);
        k_gemm<<<ngemm, 256, 0, stream>>>(Ht, Btf + (size_t)layer * 128 * K2, b + (size_t)layer * D,
                                          Ht, (layer == 2) ? out : nullptr, (layer < 2) ? 1 : 0, NN);
    }
}